// Round 1
// baseline (419.039 us; speedup 1.0000x reference)
//
#include <hip/hip_runtime.h>
#include <math.h>

#define B_ROWS 262144
#define ROWS_PER_BLOCK 8
#define THREADS (ROWS_PER_BLOCK * 32)      // 256
#define NBLOCKS (B_ROWS / ROWS_PER_BLOCK)  // 32768

// output layout (floats)
#define BARY_OFF 0
#define EV_OFF   ((size_t)B_ROWS * 128)
#define ET_OFF   ((size_t)B_ROWS * 129)
#define EB_OFF   ((size_t)B_ROWS * 130)
#define ISO_OFF  ((size_t)B_ROWS * 131)
#define LC_OFF   ((size_t)B_ROWS * 131 + 1)
#define DEC_OFF  ((size_t)B_ROWS * 131 + 2)

__device__ __forceinline__ float det4(const float* m) {
    float s0 = m[0]*m[5]  - m[1]*m[4];
    float s1 = m[0]*m[6]  - m[2]*m[4];
    float s2 = m[0]*m[7]  - m[3]*m[4];
    float s3 = m[1]*m[6]  - m[2]*m[5];
    float s4 = m[1]*m[7]  - m[3]*m[5];
    float s5 = m[2]*m[7]  - m[3]*m[6];
    float c5 = m[10]*m[15] - m[11]*m[14];
    float c4 = m[9]*m[15]  - m[11]*m[13];
    float c3 = m[9]*m[14]  - m[10]*m[13];
    float c2 = m[8]*m[15]  - m[11]*m[12];
    float c1 = m[8]*m[14]  - m[10]*m[12];
    float c0 = m[8]*m[13]  - m[9]*m[12];
    return s0*c5 - s1*c4 + s2*c3 + s3*c2 - s4*c1 + s5*c0;
}

__global__ __launch_bounds__(THREADS) void bridge_main(
    const float* __restrict__ vis, const int* __restrict__ txt,
    const float* __restrict__ Wv, const float* __restrict__ bv,
    const float* __restrict__ Wt, const float* __restrict__ bt,
    const float* __restrict__ Wd, const float* __restrict__ bd,
    float* __restrict__ out, int* __restrict__ blockCnt)
{
    __shared__ float smat[ROWS_PER_BLOCK][3][16];
    __shared__ int scnt[3];
    const int tid = threadIdx.x;
    if (tid < 3) scnt[tid] = 0;
    const int r = tid >> 5;   // row within block
    const int q = tid & 31;   // quaternion index
    const size_t row = (size_t)blockIdx.x * ROWS_PER_BLOCK + r;

    const float x0 = vis[row*3+0], x1 = vis[row*3+1], x2 = vis[row*3+2];
    const float tx = (float)txt[row];

    float v[4], t[4], b[4];
    #pragma unroll
    for (int j = 0; j < 4; ++j) {
        const int m = 4*q + j;
        v[j] = fmaf(x0, Wv[m*3+0], fmaf(x1, Wv[m*3+1], fmaf(x2, Wv[m*3+2], bv[m])));
        t[j] = fmaf(tx, Wt[m], bt[m]);
    }

    // project_to_su2: q / (norm + 1e-8)
    {
        float nv = sqrtf(v[0]*v[0]+v[1]*v[1]+v[2]*v[2]+v[3]*v[3]) + 1e-8f;
        float fv = 1.0f / nv;
        float nt = sqrtf(t[0]*t[0]+t[1]*t[1]+t[2]*t[2]+t[3]*t[3]) + 1e-8f;
        float ft = 1.0f / nt;
        #pragma unroll
        for (int j = 0; j < 4; ++j) { v[j] *= fv; t[j] *= ft; }
    }

    // karcher init: b = mean / (norm + 1e-8)
    #pragma unroll
    for (int j = 0; j < 4; ++j) b[j] = 0.5f * (v[j] + t[j]);
    {
        float nb = sqrtf(b[0]*b[0]+b[1]*b[1]+b[2]*b[2]+b[3]*b[3]) + 1e-8f;
        float fb = 1.0f / nb;
        #pragma unroll
        for (int j = 0; j < 4; ++j) b[j] *= fb;
    }

    // 5 karcher iterations
    #pragma unroll 1
    for (int it = 0; it < 5; ++it) {
        float dv = v[0]*b[0]+v[1]*b[1]+v[2]*b[2]+v[3]*b[3];
        float dt_ = t[0]*b[0]+t[1]*b[1]+t[2]*b[2]+t[3]*b[3];
        dv  = fminf(fmaxf(dv,  -1.0f + 1e-6f), 1.0f - 1e-6f);
        dt_ = fminf(fmaxf(dt_, -1.0f + 1e-6f), 1.0f - 1e-6f);
        const float thv = acosf(dv);
        const float tht = acosf(dt_);
        float pv[4], pt[4];
        #pragma unroll
        for (int j = 0; j < 4; ++j) {
            pv[j] = v[j] - dv  * b[j];
            pt[j] = t[j] - dt_ * b[j];
        }
        const float pnv = sqrtf(pv[0]*pv[0]+pv[1]*pv[1]+pv[2]*pv[2]+pv[3]*pv[3]) + 1e-8f;
        const float pnt = sqrtf(pt[0]*pt[0]+pt[1]*pt[1]+pt[2]*pt[2]+pt[3]*pt[3]) + 1e-8f;
        const float sv = 0.5f * thv / pnv;
        const float st = 0.5f * tht / pnt;
        float tg[4];
        #pragma unroll
        for (int j = 0; j < 4; ++j) tg[j] = sv * pv[j] + st * pt[j];
        const float tn = sqrtf(tg[0]*tg[0]+tg[1]*tg[1]+tg[2]*tg[2]+tg[3]*tg[3]);
        float sn_, cs_;
        __sincosf(tn, &sn_, &cs_);
        const float sfac = sn_ / (tn + 1e-8f);
        #pragma unroll
        for (int j = 0; j < 4; ++j) b[j] = cs_ * b[j] + sfac * tg[j];
        const float nb = sqrtf(b[0]*b[0]+b[1]*b[1]+b[2]*b[2]+b[3]*b[3]) + 1e-8f;
        const float fb = 1.0f / nb;
        #pragma unroll
        for (int j = 0; j < 4; ++j) b[j] *= fb;
    }

    // barycenter store (coalesced float4)
    {
        float4 bq = make_float4(b[0], b[1], b[2], b[3]);
        *(float4*)(out + BARY_OFF + row * 128 + 4 * q) = bq;
    }

    // decision partials: reduce across the row's 32 lanes
    float p0 = b[0]*Wd[4*q+0] + b[1]*Wd[4*q+1] + b[2]*Wd[4*q+2] + b[3]*Wd[4*q+3];
    float p1 = b[0]*Wd[128+4*q+0] + b[1]*Wd[128+4*q+1] + b[2]*Wd[128+4*q+2] + b[3]*Wd[128+4*q+3];
    #pragma unroll
    for (int off = 16; off >= 1; off >>= 1) {
        p0 += __shfl_xor(p0, off, 32);
        p1 += __shfl_xor(p1, off, 32);
    }

    // stage sampled quaternions (q = 0,8,16,24) for the dets
    if ((q & 7) == 0) {
        const int k = q >> 3;
        #pragma unroll
        for (int j = 0; j < 4; ++j) {
            smat[r][0][k*4+j] = v[j];
            smat[r][1][k*4+j] = t[j];
            smat[r][2][k*4+j] = b[j];
        }
    }
    __syncthreads();

    if (q == 0) {
        const float dV = det4(&smat[r][0][0]);
        const float dT = det4(&smat[r][1][0]);
        const float dB = det4(&smat[r][2][0]);
        const float eV = dV < 0.0f ? 1.0f : 0.0f;
        const float eT = dT < 0.0f ? 1.0f : 0.0f;
        const float eB = dB < 0.0f ? 1.0f : 0.0f;
        out[EV_OFF + row] = eV;
        out[ET_OFF + row] = eT;
        out[EB_OFF + row] = eB;
        out[DEC_OFF + row*2 + 0] = p0 + bd[0];
        out[DEC_OFF + row*2 + 1] = p1 + bd[1];
        if (eV != eB) atomicAdd(&scnt[0], 1);
        if (eT != eB) atomicAdd(&scnt[1], 1);
        if (eV != eT) atomicAdd(&scnt[2], 1);
    }
    __syncthreads();
    if (tid < 3) blockCnt[(size_t)blockIdx.x * 3 + tid] = scnt[tid];
}

__global__ __launch_bounds__(256) void bridge_finalize(
    const int* __restrict__ blockCnt, float* __restrict__ out)
{
    __shared__ int sh0[256], sh1[256], sh2[256];
    const int tid = threadIdx.x;
    int c0 = 0, c1 = 0, c2 = 0;
    for (int i = tid; i < NBLOCKS; i += 256) {
        c0 += blockCnt[(size_t)i*3 + 0];
        c1 += blockCnt[(size_t)i*3 + 1];
        c2 += blockCnt[(size_t)i*3 + 2];
    }
    sh0[tid] = c0; sh1[tid] = c1; sh2[tid] = c2;
    __syncthreads();
    for (int s = 128; s >= 1; s >>= 1) {
        if (tid < s) { sh0[tid] += sh0[tid+s]; sh1[tid] += sh1[tid+s]; sh2[tid] += sh2[tid+s]; }
        __syncthreads();
    }
    if (tid == 0) {
        out[ISO_OFF] = sqrtf((float)sh0[0]) + sqrtf((float)sh1[0]);
        out[LC_OFF]  = (float)sh2[0] / (float)B_ROWS;
    }
}

extern "C" void kernel_launch(void* const* d_in, const int* in_sizes, int n_in,
                              void* d_out, int out_size, void* d_ws, size_t ws_size,
                              hipStream_t stream) {
    const float* vis = (const float*)d_in[0];
    const int*   txt = (const int*)d_in[1];
    const float* Wv  = (const float*)d_in[2];
    const float* bv  = (const float*)d_in[3];
    const float* Wt  = (const float*)d_in[4];
    const float* bt  = (const float*)d_in[5];
    const float* Wd  = (const float*)d_in[6];
    const float* bd  = (const float*)d_in[7];
    float* out = (float*)d_out;
    int* blockCnt = (int*)d_ws;   // NBLOCKS*3 ints = 384 KiB

    bridge_main<<<NBLOCKS, THREADS, 0, stream>>>(vis, txt, Wv, bv, Wt, bt, Wd, bd, out, blockCnt);
    bridge_finalize<<<1, 256, 0, stream>>>(blockCnt, out);
}

// Round 3
// 195.079 us; speedup vs baseline: 2.1481x; 2.1481x over previous
//
#include <hip/hip_runtime.h>
#include <math.h>

#define B_ROWS 262144
#define ROWS_PER_BLOCK 8
#define THREADS (ROWS_PER_BLOCK * 32)      // 256
#define NBLOCKS (B_ROWS / ROWS_PER_BLOCK)  // 32768

// output layout (floats)
#define BARY_OFF 0
#define EV_OFF   ((size_t)B_ROWS * 128)
#define ET_OFF   ((size_t)B_ROWS * 129)
#define EB_OFF   ((size_t)B_ROWS * 130)
#define ISO_OFF  ((size_t)B_ROWS * 131)
#define LC_OFF   ((size_t)B_ROWS * 131 + 1)
#define DEC_OFF  ((size_t)B_ROWS * 131 + 2)

// guarded reciprocal-sqrt: returns a FINITE large value for s==0 so that
// 0 * rsq stays 0 (reference computes q/(norm+1e-8) -> 0 for zero rows;
// text_bytes==0 makes t_atoms exactly 0 for ~1/256 of rows).
__device__ __forceinline__ float rsq_guard(float s) {
    return __builtin_amdgcn_rsqf(fmaxf(s, 1e-14f));
}

__device__ __forceinline__ float det4(const float* m) {
    float s0 = m[0]*m[5]  - m[1]*m[4];
    float s1 = m[0]*m[6]  - m[2]*m[4];
    float s2 = m[0]*m[7]  - m[3]*m[4];
    float s3 = m[1]*m[6]  - m[2]*m[5];
    float s4 = m[1]*m[7]  - m[3]*m[5];
    float s5 = m[2]*m[7]  - m[3]*m[6];
    float c5 = m[10]*m[15] - m[11]*m[14];
    float c4 = m[9]*m[15]  - m[11]*m[13];
    float c3 = m[9]*m[14]  - m[10]*m[13];
    float c2 = m[8]*m[15]  - m[11]*m[12];
    float c1 = m[8]*m[14]  - m[10]*m[12];
    float c0 = m[8]*m[13]  - m[9]*m[12];
    return s0*c5 - s1*c4 + s2*c3 + s3*c2 - s4*c1 + s5*c0;
}

__global__ __launch_bounds__(THREADS) void bridge_main(
    const float* __restrict__ vis, const int* __restrict__ txt,
    const float* __restrict__ Wv, const float* __restrict__ bv,
    const float* __restrict__ Wt, const float* __restrict__ bt,
    const float* __restrict__ Wd, const float* __restrict__ bd,
    float* __restrict__ out, int* __restrict__ blockCnt)
{
    __shared__ float smat[ROWS_PER_BLOCK][3][16];
    __shared__ int scntP;
    const int tid = threadIdx.x;
    if (tid == 0) scntP = 0;
    const int r = tid >> 5;   // row within block
    const int q = tid & 31;   // quaternion index
    const size_t row = (size_t)blockIdx.x * ROWS_PER_BLOCK + r;

    const float x0 = vis[row*3+0], x1 = vis[row*3+1], x2 = vis[row*3+2];
    const float tx = (float)txt[row];

    // vectorized weight loads (all 16B-aligned)
    float wv[12];
    ((float4*)wv)[0] = ((const float4*)Wv)[3*q+0];
    ((float4*)wv)[1] = ((const float4*)Wv)[3*q+1];
    ((float4*)wv)[2] = ((const float4*)Wv)[3*q+2];
    const float4 bv4 = ((const float4*)bv)[q];
    const float4 wt4 = ((const float4*)Wt)[q];
    const float4 bt4 = ((const float4*)bt)[q];

    float v[4], t[4], b[4];
    v[0] = fmaf(x0, wv[0], fmaf(x1, wv[1],  fmaf(x2, wv[2],  bv4.x)));
    v[1] = fmaf(x0, wv[3], fmaf(x1, wv[4],  fmaf(x2, wv[5],  bv4.y)));
    v[2] = fmaf(x0, wv[6], fmaf(x1, wv[7],  fmaf(x2, wv[8],  bv4.z)));
    v[3] = fmaf(x0, wv[9], fmaf(x1, wv[10], fmaf(x2, wv[11], bv4.w)));
    t[0] = fmaf(tx, wt4.x, bt4.x);
    t[1] = fmaf(tx, wt4.y, bt4.y);
    t[2] = fmaf(tx, wt4.z, bt4.z);
    t[3] = fmaf(tx, wt4.w, bt4.w);

    // project_to_su2 (guarded hardware rsq)
    {
        const float fv = rsq_guard(v[0]*v[0]+v[1]*v[1]+v[2]*v[2]+v[3]*v[3]);
        const float ft = rsq_guard(t[0]*t[0]+t[1]*t[1]+t[2]*t[2]+t[3]*t[3]);
        #pragma unroll
        for (int j = 0; j < 4; ++j) { v[j] *= fv; t[j] *= ft; }
    }

    // Karcher mean of 2 points: iterations are an exact no-op
    // (perp_v + perp_t = (v+t) - 2*sqrt((1+v.t)/2)*b0 = 0), so
    // barycenter = normalize(v + t).
    #pragma unroll
    for (int j = 0; j < 4; ++j) b[j] = v[j] + t[j];
    {
        const float fb = rsq_guard(b[0]*b[0]+b[1]*b[1]+b[2]*b[2]+b[3]*b[3]);
        #pragma unroll
        for (int j = 0; j < 4; ++j) b[j] *= fb;
    }

    // barycenter store (coalesced float4)
    *(float4*)(out + BARY_OFF + row * 128 + 4 * q) = make_float4(b[0], b[1], b[2], b[3]);

    // decision partials across the row's 32 lanes
    const float4 wd0 = ((const float4*)Wd)[q];
    const float4 wd1 = ((const float4*)Wd)[32 + q];
    float p0 = b[0]*wd0.x + b[1]*wd0.y + b[2]*wd0.z + b[3]*wd0.w;
    float p1 = b[0]*wd1.x + b[1]*wd1.y + b[2]*wd1.z + b[3]*wd1.w;
    #pragma unroll
    for (int off = 16; off >= 1; off >>= 1) {
        p0 += __shfl_xor(p0, off, 32);
        p1 += __shfl_xor(p1, off, 32);
    }

    // stage sampled quaternions (q = 0,8,16,24) for the dets
    if ((q & 7) == 0) {
        const int k = q >> 3;
        *(float4*)&smat[r][0][k*4] = make_float4(v[0], v[1], v[2], v[3]);
        *(float4*)&smat[r][1][k*4] = make_float4(t[0], t[1], t[2], t[3]);
        *(float4*)&smat[r][2][k*4] = make_float4(b[0], b[1], b[2], b[3]);
    }
    __syncthreads();

    // one det per lane q=0(v),1(t),2(b); eta = det<0
    int e = 0;
    if (q < 3) {
        float m[16];
        const float4* mm = (const float4*)&smat[r][q][0];
        ((float4*)m)[0] = mm[0]; ((float4*)m)[1] = mm[1];
        ((float4*)m)[2] = mm[2]; ((float4*)m)[3] = mm[3];
        e = det4(m) < 0.0f ? 1 : 0;
        out[(size_t)B_ROWS * (128 + q) + row] = (float)e;
    }
    const int eV = __shfl(e, 0, 32);
    const int eT = __shfl(e, 1, 32);
    const int eB = __shfl(e, 2, 32);
    if (q == 0) {
        const int pk = (eV ^ eB) | ((eT ^ eB) << 8) | ((eV ^ eT) << 16);
        if (pk) atomicAdd(&scntP, pk);
    }
    if (q == 3) out[DEC_OFF + row*2 + 0] = p0 + bd[0];
    if (q == 4) out[DEC_OFF + row*2 + 1] = p1 + bd[1];

    __syncthreads();
    if (tid == 0) blockCnt[blockIdx.x] = scntP;
}

__global__ __launch_bounds__(1024) void bridge_finalize(
    const int* __restrict__ blockCnt, float* __restrict__ out)
{
    __shared__ int s0[16], s1[16], s2[16];
    const int tid = threadIdx.x;
    int c0 = 0, c1 = 0, c2 = 0;
    for (int i = tid; i < NBLOCKS; i += 1024) {
        const int p = blockCnt[i];
        c0 += p & 255;
        c1 += (p >> 8) & 255;
        c2 += (p >> 16) & 255;
    }
    #pragma unroll
    for (int off = 32; off >= 1; off >>= 1) {
        c0 += __shfl_down(c0, off, 64);
        c1 += __shfl_down(c1, off, 64);
        c2 += __shfl_down(c2, off, 64);
    }
    if ((tid & 63) == 0) {
        const int w = tid >> 6;
        s0[w] = c0; s1[w] = c1; s2[w] = c2;
    }
    __syncthreads();
    if (tid == 0) {
        int t0 = 0, t1 = 0, t2 = 0;
        #pragma unroll
        for (int i = 0; i < 16; ++i) { t0 += s0[i]; t1 += s1[i]; t2 += s2[i]; }
        out[ISO_OFF] = sqrtf((float)t0) + sqrtf((float)t1);
        out[LC_OFF]  = (float)t2 / (float)B_ROWS;
    }
}

extern "C" void kernel_launch(void* const* d_in, const int* in_sizes, int n_in,
                              void* d_out, int out_size, void* d_ws, size_t ws_size,
                              hipStream_t stream) {
    const float* vis = (const float*)d_in[0];
    const int*   txt = (const int*)d_in[1];
    const float* Wv  = (const float*)d_in[2];
    const float* bv  = (const float*)d_in[3];
    const float* Wt  = (const float*)d_in[4];
    const float* bt  = (const float*)d_in[5];
    const float* Wd  = (const float*)d_in[6];
    const float* bd  = (const float*)d_in[7];
    float* out = (float*)d_out;
    int* blockCnt = (int*)d_ws;   // NBLOCKS ints = 128 KiB

    bridge_main<<<NBLOCKS, THREADS, 0, stream>>>(vis, txt, Wv, bv, Wt, bt, Wd, bd, out, blockCnt);
    bridge_finalize<<<1, 1024, 0, stream>>>(blockCnt, out);
}